// Round 12
// baseline (29516.425 us; speedup 1.0000x reference)
//
#include <hip/hip_runtime.h>

typedef __bf16 bf16;

static __device__ __forceinline__ float sigmoidf_(float x) { return 1.0f / (1.0f + expf(-x)); }

__global__ void fill_guard(float* __restrict__ utt, float v) {
  int i = blockIdx.x * 256 + threadIdx.x;
  if (i < 131072) utt[i] = v;
}

// ---------------- H = x + pos_emb (fp32, exact) ----------------
__global__ void add_pos_f32(const float* __restrict__ x, const float* __restrict__ pos,
                            float* __restrict__ H) {
  size_t i = (size_t)blockIdx.x * 256 + threadIdx.x;
  if (i >= 32768000ull) return;
  int d = (int)(i & 1023);
  int s = (int)((i >> 10) % 500);
  H[i] = x[i] + pos[(size_t)s * 1024 + d];
}

// ---------------- scalar GEMM, fp32 accumulate, mixed dtypes ----------------
// BT==1: C[m,n] = sum_k A[m,k] * B[n*ldb + k]; BT==0: B[k*ldb + n]
// A split at ksplit -> A2. EPI 0: v=acc*scale(+bias); 1: sigmoid; 2: gate mix (f32 out).
template <int EPI, int BT, typename TA, typename TA2, typename TB, typename TC>
__global__ __launch_bounds__(256, 2) void sgemm(
    const TA* __restrict__ A, const TA2* __restrict__ A2, int ksplit,
    const TB* __restrict__ B, const float* __restrict__ bias, TC* __restrict__ C,
    int M, int N, int K, int lda, int ldb, int ldc, int c_off, float scale,
    long long sA, long long sB, long long sC,
    const float* __restrict__ Gh, const bf16* __restrict__ Gm) {
  __shared__ float As[64][33];
  __shared__ float Bs[BT ? 64 : 32][BT ? 33 : 65];
  const int t = threadIdx.x;
  const long long bz = blockIdx.z;
  A += bz * sA; A2 += bz * sA; B += bz * sB; C += bz * sC;
  const int m0 = blockIdx.y * 64, n0 = blockIdx.x * 64;
  const int tm = t >> 4, tn = t & 15;
  const int rr = t >> 2, cc = (t & 3) * 8;
  const int br = t >> 3, bc = (t & 7) * 8;

  float acc[4][4] = {{0.f}};

  for (int k0 = 0; k0 < K; k0 += 32) {
    __syncthreads();
    {
      int ra = m0 + rr;
#pragma unroll
      for (int j = 0; j < 8; ++j) {
        int kg = k0 + cc + j;
        float av = 0.0f;
        if (ra < M) {
          if (kg < ksplit) av = (float)A[(size_t)ra * lda + kg];
          else             av = (float)A2[(size_t)ra * lda + (kg - ksplit)];
        }
        As[rr][cc + j] = av;
      }
    }
    if (BT) {
      int rb = n0 + rr;
#pragma unroll
      for (int j = 0; j < 8; ++j) {
        int kg = k0 + cc + j;
        Bs[rr][cc + j] = (rb < N) ? (float)B[(size_t)rb * ldb + kg] : 0.0f;
      }
    } else {
      int rk = k0 + br;
#pragma unroll
      for (int j = 0; j < 8; ++j)
        Bs[br][bc + j] = (rk < K) ? (float)B[(size_t)rk * ldb + n0 + bc + j] : 0.0f;
    }
    __syncthreads();
#pragma unroll 8
    for (int kk = 0; kk < 32; ++kk) {
      float a4[4], b4[4];
#pragma unroll
      for (int im = 0; im < 4; ++im) a4[im] = As[tm * 4 + im][kk];
#pragma unroll
      for (int jn = 0; jn < 4; ++jn) b4[jn] = BT ? Bs[tn * 4 + jn][kk] : Bs[kk][tn * 4 + jn];
#pragma unroll
      for (int im = 0; im < 4; ++im)
#pragma unroll
        for (int jn = 0; jn < 4; ++jn) acc[im][jn] += a4[im] * b4[jn];
    }
  }

#pragma unroll
  for (int im = 0; im < 4; ++im) {
    int m = m0 + tm * 4 + im;
    if (m >= M) continue;
#pragma unroll
    for (int jn = 0; jn < 4; ++jn) {
      int n = n0 + tn * 4 + jn;
      if (n >= N) continue;
      float v = acc[im][jn] * scale;
      if (bias) v += bias[n];
      if (EPI == 1) v = sigmoidf_(v);
      if (EPI == 2) {
        float g = sigmoidf_(v);
        float h  = Gh[(size_t)m * 1024 + n];
        float hm = (float)Gm[(size_t)m * 1024 + n];
        v = g * h + (1.0f - g) * hm;
      }
      C[(size_t)m * ldc + c_off + n] = (TC)v;
    }
  }
}

// ---------------- masked softmax on fp32 scores, one thread per row ----------------
__global__ void attn_softmax_f32(float* __restrict__ S, int fw) {
  int row = blockIdx.x * 256 + threadIdx.x;
  if (row >= 32000) return;
  int q = row % 500;
  float* Srow = S + (size_t)row * 512;
  int klo = fw ? 0 : q;
  int khi = fw ? q : 499;
  float m = -1e30f;
  for (int k = klo; k <= khi; ++k) m = fmaxf(m, Srow[k]);
  float sum = 0.0f;
  for (int k = klo; k <= khi; ++k) sum += expf(Srow[k] - m);
  float inv = 1.0f / sum;
  for (int k = 0; k < 512; ++k) {
    float p = (k >= klo && k <= khi) ? expf(Srow[k] - m) * inv : 0.0f;
    Srow[k] = p;
  }
}

// ---------------- final: softmax over seq + weighted sum -> f32 utt in d_out ----------------
__global__ void final_reduce_f32(const float* __restrict__ scores2, const float* __restrict__ Ci,
                                 float* __restrict__ utt) {
  int c = blockIdx.x * 256 + threadIdx.x;
  int b = blockIdx.y;
  if (c >= 2048 || b >= 64) return;
  float m = -1e30f;
  for (int s = 0; s < 500; ++s) {
    float x = scores2[((size_t)(b * 500 + s)) * 2048 + c];
    m = fmaxf(m, x);
  }
  float sum = 0.0f, acc = 0.0f;
  for (int s = 0; s < 500; ++s) {
    size_t idx = ((size_t)(b * 500 + s)) * 2048 + c;
    float e = expf(scores2[idx] - m);
    sum += e;
    acc += e * Ci[idx];
  }
  utt[(size_t)b * 2048 + c] = acc / sum;
}

// ---------------- launcher ----------------
extern "C" void kernel_launch(void* const* d_in, const int* in_sizes, int n_in,
                              void* d_out, int out_size, void* d_ws, size_t ws_size,
                              hipStream_t stream) {
  (void)in_sizes; (void)n_in; (void)out_size;
  // d_out is FLOAT32: utt f32 [64][2048] @ word 0; C_i f32 [64][500][2048] @ word 131072
  float* utt = (float*)d_out;
  float* Ci  = (float*)d_out + 131072;

  const float* x     = (const float*)d_in[0];
  const float* pos   = (const float*)d_in[1];
  const float* Wq_fw = (const float*)d_in[2];  const float* bq_fw = (const float*)d_in[3];
  const float* Wk_fw = (const float*)d_in[4];  const float* bk_fw = (const float*)d_in[5];
  const float* Wv_fw = (const float*)d_in[6];  const float* bv_fw = (const float*)d_in[7];
  const float* Wq_bw = (const float*)d_in[8];  const float* bq_bw = (const float*)d_in[9];
  const float* Wk_bw = (const float*)d_in[10]; const float* bk_bw = (const float*)d_in[11];
  const float* Wv_bw = (const float*)d_in[12]; const float* bv_bw = (const float*)d_in[13];
  const float* Wg_fw = (const float*)d_in[14]; const float* bg_fw = (const float*)d_in[15];
  const float* Wg_bw = (const float*)d_in[16]; const float* bg_bw = (const float*)d_in[17];
  const float* W2    = (const float*)d_in[18]; const float* b2    = (const float*)d_in[19];
  const float* W1    = (const float*)d_in[20]; const float* b1    = (const float*)d_in[21];

  // ws (bytes): H f32 @0 (131,072,000) | Q bf16 @131,072,000 | K bf16 @196,608,000 |
  //             V bf16 @262,144,000 | S f32 @327,680,000 | Hm bf16 @393,216,000
  // aliases after attention: activ bf16 @131,072,000 (Q/K); scores2 f32 @262,144,000 (V+S)
  const size_t WS_BYTES = 458752000ull;
  if (ws_size < WS_BYTES) { fill_guard<<<512, 256, 0, stream>>>(utt, 500.0f); return; }

  char* wsb = (char*)d_ws;
  float* Hb  = (float*)(wsb);
  bf16*  Qb  = (bf16*)(wsb + 131072000);
  bf16*  Kb  = (bf16*)(wsb + 196608000);
  bf16*  Vb  = (bf16*)(wsb + 262144000);
  float* Sb  = (float*)(wsb + 327680000);
  bf16*  Hmb = (bf16*)(wsb + 393216000);
  bf16*  activ   = (bf16*)(wsb + 131072000);   // alias [Q,K)
  float* scores2 = (float*)(wsb + 262144000);  // alias [V,S) = 131,072,000 B

  add_pos_f32<<<128000, 256, 0, stream>>>(x, pos, Hb);

  const int BIG = 1 << 30;
  for (int dir = 0; dir < 2; ++dir) {
    const float* Wq = dir ? Wq_bw : Wq_fw;  const float* bq = dir ? bq_bw : bq_fw;
    const float* Wk = dir ? Wk_bw : Wk_fw;  const float* bk = dir ? bk_bw : bk_fw;
    const float* Wv = dir ? Wv_bw : Wv_fw;  const float* bv = dir ? bv_bw : bv_fw;
    const float* Wg = dir ? Wg_bw : Wg_fw;  const float* bg = dir ? bg_bw : bg_fw;

    sgemm<0, 0, float, float, float, bf16><<<dim3(16, 500, 1), 256, 0, stream>>>(
        Hb, Hb, BIG, Wq, bq, Qb, 32000, 1024, 1024, 1024, 1024, 1024, 0, 1.0f,
        0, 0, 0, nullptr, nullptr);
    sgemm<0, 0, float, float, float, bf16><<<dim3(16, 500, 1), 256, 0, stream>>>(
        Hb, Hb, BIG, Wk, bk, Kb, 32000, 1024, 1024, 1024, 1024, 1024, 0, 1.0f,
        0, 0, 0, nullptr, nullptr);
    sgemm<0, 0, float, float, float, bf16><<<dim3(16, 500, 1), 256, 0, stream>>>(
        Hb, Hb, BIG, Wv, bv, Vb, 32000, 1024, 1024, 1024, 1024, 1024, 0, 1.0f,
        0, 0, 0, nullptr, nullptr);
    // scores = Q K^T / 32 -> f32 S [64][500][512]
    sgemm<0, 1, bf16, bf16, bf16, float><<<dim3(8, 8, 64), 256, 0, stream>>>(
        Qb, Qb, BIG, Kb, nullptr, Sb, 500, 500, 1024, 1024, 1024, 512, 0, 0.03125f,
        512000, 512000, 256000, nullptr, nullptr);
    attn_softmax_f32<<<125, 256, 0, stream>>>(Sb, dir == 0 ? 1 : 0);
    // Hm = P @ V
    sgemm<0, 0, float, float, bf16, bf16><<<dim3(16, 8, 64), 256, 0, stream>>>(
        Sb, Sb, BIG, Vb, nullptr, Hmb, 500, 1024, 500, 512, 1024, 1024, 0, 1.0f,
        256000, 512000, 512000, nullptr, nullptr);
    // gate -> f32 C_i half in d_out
    sgemm<2, 0, float, bf16, float, float><<<dim3(16, 500, 1), 256, 0, stream>>>(
        Hb, Hmb, 1024, Wg, bg, Ci, 32000, 1024, 2048, 1024, 1024, 2048,
        dir == 0 ? 0 : 1024, 1.0f, 0, 0, 0, Hb, Hmb);
  }

  // activ = sigmoid(Ci_f32 @ W2 + b2) -> bf16
  sgemm<1, 0, float, float, float, bf16><<<dim3(32, 500, 1), 256, 0, stream>>>(
      Ci, Ci, BIG, W2, b2, activ, 32000, 2048, 2048, 2048, 2048, 2048, 0, 1.0f,
      0, 0, 0, nullptr, nullptr);
  // scores2 = activ @ W1 + b1 -> f32
  sgemm<0, 0, bf16, bf16, float, float><<<dim3(32, 500, 1), 256, 0, stream>>>(
      activ, activ, BIG, W1, b1, scores2, 32000, 2048, 2048, 2048, 2048, 2048, 0, 1.0f,
      0, 0, 0, nullptr, nullptr);
  // utt (f32, directly into d_out)
  final_reduce_f32<<<dim3(8, 64), 256, 0, stream>>>(scores2, Ci, utt);
}

// Round 13
// 4168.374 us; speedup vs baseline: 7.0810x; 7.0810x over previous
//
#include <hip/hip_runtime.h>

typedef __bf16 bf16;
typedef __bf16 bf16x8 __attribute__((ext_vector_type(8)));
typedef float  f32x4  __attribute__((ext_vector_type(4)));

static __device__ __forceinline__ float sigmoidf_(float x) { return 1.0f / (1.0f + expf(-x)); }

__global__ void fill_guard(float* __restrict__ utt, float v) {
  int i = blockIdx.x * 256 + threadIdx.x;
  if (i < 131072) utt[i] = v;
}

// ---------------- H = x + pos_emb (fp32, exact) ----------------
__global__ void add_pos_f32(const float* __restrict__ x, const float* __restrict__ pos,
                            float* __restrict__ H) {
  size_t i = (size_t)blockIdx.x * 256 + threadIdx.x;
  if (i >= 32768000ull) return;
  int d = (int)(i & 1023);
  int s = (int)((i >> 10) % 500);
  H[i] = x[i] + pos[(size_t)s * 1024 + d];
}

// ---------------- weight transpose+convert: fp32 [R][C] -> bf16 [C][R] ----------------
__global__ void wtrans(const float* __restrict__ src, bf16* __restrict__ dst, int R, int C) {
  __shared__ float tile[32][33];
  int c0 = blockIdx.x * 32, r0 = blockIdx.y * 32;
  int tr = threadIdx.x >> 5, tc = threadIdx.x & 31;
#pragma unroll
  for (int i = 0; i < 4; ++i)
    tile[tr + i * 8][tc] = src[(size_t)(r0 + tr + i * 8) * C + c0 + tc];
  __syncthreads();
#pragma unroll
  for (int i = 0; i < 4; ++i) {
    int rr = tr + i * 8;
    dst[(size_t)(c0 + rr) * R + r0 + tc] = (bf16)tile[tc][rr];
  }
}

// ---------------- staging loads: 8 contiguous elems -> bf16x8 ----------------
__device__ __forceinline__ bf16x8 ld8(const bf16* p) { return *(const bf16x8*)p; }
__device__ __forceinline__ bf16x8 ld8(const float* p) {
  float4 a = *(const float4*)p;
  float4 b = *(const float4*)(p + 4);
  bf16x8 r;
  r[0] = (bf16)a.x; r[1] = (bf16)a.y; r[2] = (bf16)a.z; r[3] = (bf16)a.w;
  r[4] = (bf16)b.x; r[5] = (bf16)b.y; r[6] = (bf16)b.z; r[7] = (bf16)b.w;
  return r;
}

// ---------------- MFMA GEMM: C[m,n] = scale*sum_k A[m,k]*Bt[n,k] (+bias) + epilogue ----
// 128x128 tile, BK=32, 4 waves. A: TA (f32 converted or bf16); split at ksplit -> A2 (TA2).
// Bt: bf16 [N][K]. EPI 0: plain (TC f32 or bf16). EPI 1: sigmoid. EPI 2: gate mix ->
// v = g*Gh_f32[m,n] + (1-g)*Gm_bf16[m,n]. EPI 3: V^T write: C[b*524288 + n*512 + s], m=b*500+s.
template <int EPI, typename TA, typename TA2, typename TC>
__global__ __launch_bounds__(256, 2) void mgemm(
    const TA* __restrict__ A, const TA2* __restrict__ A2, int ksplit,
    const bf16* __restrict__ Bt, const float* __restrict__ bias, TC* __restrict__ C,
    int M, int N, int K, int lda, int ldb, int ldc, int c_off, float scale,
    long long sA, long long sB, long long sC,
    const float* __restrict__ Gh, const bf16* __restrict__ Gm) {
  __shared__ __align__(16) char sm[16384];  // A tile [128][32]bf16 @0, B tile @8192
  const int t = threadIdx.x;
  const long long bz = blockIdx.z;
  A += bz * sA; A2 += bz * sA; Bt += bz * sB; C += bz * sC;
  const int m0 = blockIdx.y * 128, n0 = blockIdx.x * 128;

  f32x4 acc[4][4];
#pragma unroll
  for (int i = 0; i < 4; ++i)
#pragma unroll
    for (int j = 0; j < 4; ++j)
#pragma unroll
      for (int c = 0; c < 4; ++c) acc[i][j][c] = 0.0f;

  const int lane = t & 63;
  const int wv = t >> 6, wm = (wv >> 1) * 64, wn = (wv & 1) * 64;
  const int lr = lane & 15, lkb = (lane >> 4) * 16;  // frag row, k-byte offset in 64B row
  const int rr = t >> 2, cc = (t & 3) * 8;           // staging row, col (elems)

  for (int k0 = 0; k0 < K; k0 += 32) {
    bf16x8 sa[2], sb[2];
    const bool useA2 = (k0 >= ksplit);
#pragma unroll
    for (int j = 0; j < 2; ++j) {
      int ra = m0 + j * 64 + rr; ra = ra < M ? ra : M - 1;
      sa[j] = useA2 ? ld8(A2 + (size_t)ra * lda + (k0 - ksplit) + cc)
                    : ld8(A  + (size_t)ra * lda + k0 + cc);
      int rb = n0 + j * 64 + rr; rb = rb < N ? rb : N - 1;
      sb[j] = ld8(Bt + (size_t)rb * ldb + k0 + cc);
    }
    __syncthreads();  // prev iteration's frag reads done
#pragma unroll
    for (int j = 0; j < 2; ++j) {
      *(bf16x8*)(sm + j * 4096 + t * 16) = sa[j];
      *(bf16x8*)(sm + 8192 + j * 4096 + t * 16) = sb[j];
    }
    __syncthreads();  // tiles visible

    bf16x8 av[4], bv[4];
#pragma unroll
    for (int i = 0; i < 4; ++i) {
      av[i] = *(const bf16x8*)(sm + (wm + i * 16 + lr) * 64 + lkb);
      bv[i] = *(const bf16x8*)(sm + 8192 + (wn + i * 16 + lr) * 64 + lkb);
    }
#pragma unroll
    for (int i = 0; i < 4; ++i)
#pragma unroll
      for (int j = 0; j < 4; ++j)
        acc[i][j] = __builtin_amdgcn_mfma_f32_16x16x32_bf16(av[i], bv[j], acc[i][j], 0, 0, 0);
  }

  // D elem j4 of frag (i,j): row = wm+i*16+(lane>>4)*4+j4, col = wn+j*16+(lane&15)
#pragma unroll
  for (int i = 0; i < 4; ++i) {
#pragma unroll
    for (int j4 = 0; j4 < 4; ++j4) {
      int m = m0 + wm + i * 16 + (lane >> 4) * 4 + j4;
      if (m >= M) continue;
#pragma unroll
      for (int j = 0; j < 4; ++j) {
        int n = n0 + wn + j * 16 + (lane & 15);
        if (n >= N) continue;
        float v = acc[i][j][j4] * scale;
        if (bias) v += bias[n];
        if (EPI == 1) v = sigmoidf_(v);
        if (EPI == 2) {
          float g = sigmoidf_(v);
          float h  = Gh[(size_t)m * 1024 + n];
          float hm = (float)Gm[(size_t)m * 1024 + n];
          v = g * h + (1.0f - g) * hm;
        }
        if (EPI == 3) {
          unsigned b = (unsigned)m / 500u;
          unsigned s = (unsigned)m - b * 500u;
          C[(size_t)b * 524288 + (size_t)n * 512 + s] = (TC)v;
        } else {
          C[(size_t)m * ldc + c_off + n] = (TC)v;
        }
      }
    }
  }
}

// ---------------- masked softmax: S f32 -> P bf16 (pads zero), one thread per row ------
__global__ void attn_softmax_p(const float* __restrict__ S, bf16* __restrict__ P, int fw) {
  int row = blockIdx.x * 256 + threadIdx.x;
  if (row >= 32000) return;
  int q = row % 500;
  const float* Srow = S + (size_t)row * 512;
  bf16* Prow = P + (size_t)row * 512;
  int klo = fw ? 0 : q;
  int khi = fw ? q : 499;
  float m = -1e30f;
  for (int k = klo; k <= khi; ++k) m = fmaxf(m, Srow[k]);
  float sum = 0.0f;
  for (int k = klo; k <= khi; ++k) sum += expf(Srow[k] - m);
  float inv = 1.0f / sum;
  for (int k = 0; k < 512; ++k)
    Prow[k] = (k >= klo && k <= khi) ? (bf16)(expf(Srow[k] - m) * inv) : (bf16)0.0f;
}

// ---------------- final: softmax over seq + weighted sum (per 32-batch chunk) ----------
__global__ void final_reduce_chunk(const float* __restrict__ s2, const float* __restrict__ Ci,
                                   float* __restrict__ utt) {
  int c = blockIdx.x * 256 + threadIdx.x;
  int b = blockIdx.y;  // chunk-local batch
  if (c >= 2048) return;
  float m = -1e30f;
  for (int s = 0; s < 500; ++s) m = fmaxf(m, s2[((size_t)(b * 500 + s)) * 2048 + c]);
  float sum = 0.0f, acc = 0.0f;
  for (int s = 0; s < 500; ++s) {
    size_t idx = ((size_t)(b * 500 + s)) * 2048 + c;
    float e = expf(s2[idx] - m);
    sum += e;
    acc += e * Ci[idx];
  }
  utt[(size_t)b * 2048 + c] = acc / sum;
}

// ---------------- launcher ----------------
extern "C" void kernel_launch(void* const* d_in, const int* in_sizes, int n_in,
                              void* d_out, int out_size, void* d_ws, size_t ws_size,
                              hipStream_t stream) {
  (void)in_sizes; (void)n_in; (void)out_size;
  float* utt = (float*)d_out;                // f32 [64][2048]
  float* Ci  = (float*)d_out + 131072;       // f32 [32000][2048]

  const float* x     = (const float*)d_in[0];
  const float* pos   = (const float*)d_in[1];
  const float* Wq_fw = (const float*)d_in[2];  const float* bq_fw = (const float*)d_in[3];
  const float* Wk_fw = (const float*)d_in[4];  const float* bk_fw = (const float*)d_in[5];
  const float* Wv_fw = (const float*)d_in[6];  const float* bv_fw = (const float*)d_in[7];
  const float* Wq_bw = (const float*)d_in[8];  const float* bq_bw = (const float*)d_in[9];
  const float* Wk_bw = (const float*)d_in[10]; const float* bk_bw = (const float*)d_in[11];
  const float* Wv_bw = (const float*)d_in[12]; const float* bv_bw = (const float*)d_in[13];
  const float* Wg_fw = (const float*)d_in[14]; const float* bg_fw = (const float*)d_in[15];
  const float* Wg_bw = (const float*)d_in[16]; const float* bg_bw = (const float*)d_in[17];
  const float* W2    = (const float*)d_in[18]; const float* b2    = (const float*)d_in[19];
  const float* W1    = (const float*)d_in[20]; const float* b1    = (const float*)d_in[21];

  // ws layout (bytes), total 465,305,600 (guard-proven):
  //  s2buf/H f32 @0                (131,072,000)   H: t0->gate dir1; s2buf: chunks at end
  //  Q bf16 @131,072,000           ( 65,536,000)   } activ bf16 aliases Q+K after dir1
  //  K bf16 @196,608,000           ( 65,536,000)   }
  //  Vt bf16 @262,144,000          ( 67,108,864)   [64][1024][512]
  //  S f32 @329,252,864            ( 65,536,000)   Hm bf16 aliases S after softmax
  //  P bf16 @394,788,864           ( 32,768,000)
  //  weights bf16 @427,556,864     ( 37,748,736)
  const size_t WS_BYTES = 465305600ull;
  if (ws_size < WS_BYTES) { fill_guard<<<512, 256, 0, stream>>>(utt, 500.0f); return; }

  char* wsb = (char*)d_ws;
  float* Hb   = (float*)(wsb);
  float* s2b  = (float*)(wsb);                 // alias H (dead by scores2 time)
  bf16*  Qb   = (bf16*)(wsb + 131072000);
  bf16*  Kb   = (bf16*)(wsb + 196608000);
  bf16*  Vt   = (bf16*)(wsb + 262144000);
  float* Sb   = (float*)(wsb + 329252864);
  bf16*  Hmb  = (bf16*)(wsb + 329252864);      // alias S (dead after softmax)
  bf16*  Pb   = (bf16*)(wsb + 394788864);
  char*  wts  = wsb + 427556864;
  bf16* WqF = (bf16*)(wts);             bf16* WkF = (bf16*)(wts + 2097152);
  bf16* WvF = (bf16*)(wts + 4194304);   bf16* WqB = (bf16*)(wts + 6291456);
  bf16* WkB = (bf16*)(wts + 8388608);   bf16* WvB = (bf16*)(wts + 10485760);
  bf16* WgF = (bf16*)(wts + 12582912);  bf16* WgB = (bf16*)(wts + 16777216);
  bf16* W2t = (bf16*)(wts + 20971520);  bf16* W1t = (bf16*)(wts + 29360128);
  bf16* activ = (bf16*)(wsb + 131072000);      // alias Q+K (dead after dir1)

  add_pos_f32<<<128000, 256, 0, stream>>>(x, pos, Hb);

  struct WT { const float* s; bf16* d; int R, C; } wt[10] = {
      {Wq_fw, WqF, 1024, 1024}, {Wk_fw, WkF, 1024, 1024}, {Wv_fw, WvF, 1024, 1024},
      {Wq_bw, WqB, 1024, 1024}, {Wk_bw, WkB, 1024, 1024}, {Wv_bw, WvB, 1024, 1024},
      {Wg_fw, WgF, 2048, 1024}, {Wg_bw, WgB, 2048, 1024},
      {W2,    W2t, 2048, 2048}, {W1,    W1t, 2048, 2048}};
  for (int i = 0; i < 10; ++i)
    wtrans<<<dim3(wt[i].C / 32, wt[i].R / 32), 256, 0, stream>>>(wt[i].s, wt[i].d, wt[i].R, wt[i].C);

  const int BIG = 1 << 30;
  for (int dir = 0; dir < 2; ++dir) {
    const bf16* WqT = dir ? WqB : WqF;  const float* bq = dir ? bq_bw : bq_fw;
    const bf16* WkT = dir ? WkB : WkF;  const float* bk = dir ? bk_bw : bk_fw;
    const bf16* WvT = dir ? WvB : WvF;  const float* bv = dir ? bv_bw : bv_fw;
    const bf16* WgT = dir ? WgB : WgF;  const float* bg = dir ? bg_bw : bg_fw;

    // Q = H @ Wq + bq   [32000,1024]
    mgemm<0, float, float, bf16><<<dim3(8, 250, 1), 256, 0, stream>>>(
        Hb, Hb, BIG, WqT, bq, Qb, 32000, 1024, 1024, 1024, 1024, 1024, 0, 1.0f,
        0, 0, 0, nullptr, nullptr);
    mgemm<0, float, float, bf16><<<dim3(8, 250, 1), 256, 0, stream>>>(
        Hb, Hb, BIG, WkT, bk, Kb, 32000, 1024, 1024, 1024, 1024, 1024, 0, 1.0f,
        0, 0, 0, nullptr, nullptr);
    // V written directly transposed per batch: Vt[b][d][s]
    mgemm<3, float, float, bf16><<<dim3(8, 250, 1), 256, 0, stream>>>(
        Hb, Hb, BIG, WvT, bv, Vt, 32000, 1024, 1024, 1024, 1024, 512, 0, 1.0f,
        0, 0, 0, nullptr, nullptr);
    // S = Q K^T / 32   f32 [64][500][512]
    mgemm<0, bf16, bf16, float><<<dim3(4, 4, 64), 256, 0, stream>>>(
        Qb, Qb, BIG, Kb, nullptr, Sb, 500, 500, 1024, 1024, 1024, 512, 0, 0.03125f,
        512000, 512000, 256000, nullptr, nullptr);
    // P = masked softmax(S)  bf16 (pads zero)
    attn_softmax_p<<<125, 256, 0, stream>>>(Sb, Pb, dir == 0 ? 1 : 0);
    // Hm = P @ V   (K=512, P pads zero)  -> overwrites S region
    mgemm<0, bf16, bf16, bf16><<<dim3(8, 4, 64), 256, 0, stream>>>(
        Pb, Pb, BIG, Vt, nullptr, Hmb, 500, 1024, 512, 512, 512, 1024, 0, 1.0f,
        256000, 524288, 512000, nullptr, nullptr);
    // C_i half = gate mix, f32 into d_out
    mgemm<2, float, bf16, float><<<dim3(8, 250, 1), 256, 0, stream>>>(
        Hb, Hmb, 1024, WgT, bg, Ci, 32000, 1024, 2048, 1024, 2048, 2048,
        dir == 0 ? 0 : 1024, 1.0f, 0, 0, 0, Hb, Hmb);
  }

  // activ = sigmoid(Ci @ W2 + b2) -> bf16 over Q/K region
  mgemm<1, float, float, bf16><<<dim3(16, 250, 1), 256, 0, stream>>>(
      Ci, Ci, BIG, W2t, b2, activ, 32000, 2048, 2048, 2048, 2048, 2048, 0, 1.0f,
      0, 0, 0, nullptr, nullptr);

  // scores2 + final reduce in 2 chunks of 32 batches (s2buf reuses H region)
  for (int c0 = 0; c0 < 2; ++c0) {
    mgemm<0, bf16, bf16, float><<<dim3(16, 125, 1), 256, 0, stream>>>(
        activ + (size_t)c0 * 16000 * 2048, activ, BIG, W1t, b1, s2b,
        16000, 2048, 2048, 2048, 2048, 2048, 0, 1.0f, 0, 0, 0, nullptr, nullptr);
    final_reduce_chunk<<<dim3(8, 32), 256, 0, stream>>>(
        s2b, Ci + (size_t)c0 * 32 * 500 * 2048, utt + (size_t)c0 * 32 * 2048);
  }
}

// Round 15
// 3576.181 us; speedup vs baseline: 8.2536x; 1.1656x over previous
//
#include <hip/hip_runtime.h>

typedef __bf16 bf16;
typedef __bf16 bf16x4 __attribute__((ext_vector_type(4)));
typedef __bf16 bf16x8 __attribute__((ext_vector_type(8)));
typedef float  f32x4  __attribute__((ext_vector_type(4)));
typedef unsigned int u32;

#define GLD_LDS16(gsrc, ldst) \
  __builtin_amdgcn_global_load_lds((const __attribute__((address_space(1))) u32*)(gsrc), \
                                   (__attribute__((address_space(3))) u32*)(ldst), 16, 0, 0)

static __device__ __forceinline__ float sigmoidf_(float x) { return 1.0f / (1.0f + expf(-x)); }

__global__ void fill_guard(float* __restrict__ utt, float v) {
  int i = blockIdx.x * 256 + threadIdx.x;
  if (i < 131072) utt[i] = v;
}

// ---------------- H = bf16(x + pos_emb) ----------------
__global__ void add_pos_bf(const float* __restrict__ x, const float* __restrict__ pos,
                           bf16* __restrict__ H) {
  size_t i = ((size_t)blockIdx.x * 256 + threadIdx.x) * 4;
  if (i >= 32768000ull) return;
  int d = (int)(i & 1023);
  int s = (int)((i >> 10) % 500);
  float4 xv = *(const float4*)(x + i);
  float4 pv = *(const float4*)(pos + (size_t)s * 1024 + d);
  bf16x4 o;
  o[0] = (bf16)(xv.x + pv.x); o[1] = (bf16)(xv.y + pv.y);
  o[2] = (bf16)(xv.z + pv.z); o[3] = (bf16)(xv.w + pv.w);
  *(bf16x4*)(H + i) = o;
}

// ---------------- weight transpose+convert: fp32 [R][C] -> bf16 [C][R] ----------------
__global__ void wtrans(const float* __restrict__ src, bf16* __restrict__ dst, int R, int C) {
  __shared__ float tile[32][33];
  int c0 = blockIdx.x * 32, r0 = blockIdx.y * 32;
  int tr = threadIdx.x >> 5, tc = threadIdx.x & 31;
#pragma unroll
  for (int i = 0; i < 4; ++i)
    tile[tr + i * 8][tc] = src[(size_t)(r0 + tr + i * 8) * C + c0 + tc];
  __syncthreads();
#pragma unroll
  for (int i = 0; i < 4; ++i) {
    int rr = tr + i * 8;
    dst[(size_t)(c0 + rr) * R + r0 + tc] = (bf16)tile[tc][rr];
  }
}

// ---------------- Ci f32 -> bf16 convert ----------------
__global__ void ci2bf(const float* __restrict__ src, bf16* __restrict__ dst) {
  size_t i = ((size_t)blockIdx.x * 256 + threadIdx.x) * 4;
  if (i >= 65536000ull) return;
  float4 v = *(const float4*)(src + i);
  bf16x4 o;
  o[0] = (bf16)v.x; o[1] = (bf16)v.y; o[2] = (bf16)v.z; o[3] = (bf16)v.w;
  *(bf16x4*)(dst + i) = o;
}

// ---------------- MFMA GEMM, global_load_lds staging, all-bf16 operands ----------------
// C[m,n] = scale*sum_k A[m,k]*Bt[n,k] (+bias[n]) + epilogue.  128x128 tile, BK=32, 4 waves.
// A split at ksplit -> A2 (same lda). EPI 0: plain. 1: sigmoid. 2: gate mix
// v=g*Gh[m,n]+(1-g)*Gm[m,n] (both bf16 [*,1024]). 3: V^T write C[b*524288+n*512+s], m=b*500+s.
template <int EPI, typename TC>
__global__ __launch_bounds__(256, 2) void mgemm(
    const bf16* __restrict__ A, const bf16* __restrict__ A2, int ksplit,
    const bf16* __restrict__ Bt, const float* __restrict__ bias, TC* __restrict__ C,
    int M, int N, int K, int lda, int ldb, int ldc, int c_off, float scale,
    long long sA, long long sB, long long sC,
    const bf16* __restrict__ Gh, const bf16* __restrict__ Gm) {
  __shared__ __align__(16) char sm[16384];  // A tile [128][32] @0, B tile @8192
  const int t = threadIdx.x;
  const long long bz = blockIdx.z;
  A += bz * sA; A2 += bz * sA; Bt += bz * sB; C += bz * sC;
  const int m0 = blockIdx.y * 128, n0 = blockIdx.x * 128;

  f32x4 acc[4][4];
#pragma unroll
  for (int i = 0; i < 4; ++i)
#pragma unroll
    for (int j = 0; j < 4; ++j)
#pragma unroll
      for (int c = 0; c < 4; ++c) acc[i][j][c] = 0.0f;

  const int lane = t & 63;
  const int wv = t >> 6, wm = (wv >> 1) * 64, wn = (wv & 1) * 64;
  const int lr = lane & 15, lkb = (lane >> 4) * 16;
  const int rr = t >> 2, cc = (t & 3) * 8;

  for (int k0 = 0; k0 < K; k0 += 32) {
    const bf16* Ak = (k0 < ksplit) ? (A + k0) : (A2 + (k0 - ksplit));
    const bf16* Bk = Bt + k0;
#pragma unroll
    for (int j = 0; j < 2; ++j) {
      int ra = m0 + j * 64 + rr; ra = ra < M ? ra : M - 1;
      GLD_LDS16(Ak + (size_t)ra * lda + cc, sm + j * 4096 + t * 16);
      int rb = n0 + j * 64 + rr; rb = rb < N ? rb : N - 1;
      GLD_LDS16(Bk + (size_t)rb * ldb + cc, sm + 8192 + j * 4096 + t * 16);
    }
    asm volatile("s_waitcnt vmcnt(0)" ::: "memory");
    __syncthreads();

    bf16x8 av[4], bv[4];
#pragma unroll
    for (int i = 0; i < 4; ++i) {
      av[i] = *(const bf16x8*)(sm + (wm + i * 16 + lr) * 64 + lkb);
      bv[i] = *(const bf16x8*)(sm + 8192 + (wn + i * 16 + lr) * 64 + lkb);
    }
#pragma unroll
    for (int i = 0; i < 4; ++i)
#pragma unroll
      for (int j = 0; j < 4; ++j)
        acc[i][j] = __builtin_amdgcn_mfma_f32_16x16x32_bf16(av[i], bv[j], acc[i][j], 0, 0, 0);
    __syncthreads();
  }

  // D elem j4 of frag (i,j): row = wm+i*16+(lane>>4)*4+j4, col = wn+j*16+(lane&15)
#pragma unroll
  for (int i = 0; i < 4; ++i) {
#pragma unroll
    for (int j4 = 0; j4 < 4; ++j4) {
      int m = m0 + wm + i * 16 + (lane >> 4) * 4 + j4;
      if (m >= M) continue;
#pragma unroll
      for (int j = 0; j < 4; ++j) {
        int n = n0 + wn + j * 16 + (lane & 15);
        if (n >= N) continue;
        float v = acc[i][j][j4] * scale;
        if (bias) v += bias[n];
        if (EPI == 1) v = sigmoidf_(v);
        if (EPI == 2) {
          float g = sigmoidf_(v);
          float h  = (float)Gh[(size_t)m * 1024 + n];
          float hm = (float)Gm[(size_t)m * 1024 + n];
          v = g * h + (1.0f - g) * hm;
        }
        if (EPI == 3) {
          unsigned b = (unsigned)m / 500u;
          unsigned s = (unsigned)m - b * 500u;
          C[(size_t)b * 524288 + (size_t)n * 512 + s] = (TC)v;
        } else {
          C[(size_t)m * ldc + c_off + n] = (TC)v;
        }
      }
    }
  }
}

// ---------------- masked softmax: S f32 -> P bf16 (pads zero), one thread per row ------
__global__ void attn_softmax_p(const float* __restrict__ S, bf16* __restrict__ P, int fw) {
  int row = blockIdx.x * 256 + threadIdx.x;
  if (row >= 32000) return;
  int q = row % 500;
  const float* Srow = S + (size_t)row * 512;
  bf16* Prow = P + (size_t)row * 512;
  int klo = fw ? 0 : q;
  int khi = fw ? q : 499;
  float m = -1e30f;
  for (int k = klo; k <= khi; ++k) m = fmaxf(m, Srow[k]);
  float sum = 0.0f;
  for (int k = klo; k <= khi; ++k) sum += expf(Srow[k] - m);
  float inv = 1.0f / sum;
  for (int k = 0; k < 512; ++k)
    Prow[k] = (k >= klo && k <= khi) ? (bf16)(expf(Srow[k] - m) * inv) : (bf16)0.0f;
}

// ---------------- final: softmax over seq + weighted sum (per 32-batch chunk) ----------
__global__ void final_reduce_chunk(const float* __restrict__ s2, const float* __restrict__ Ci,
                                   float* __restrict__ utt) {
  int c = blockIdx.x * 256 + threadIdx.x;
  int b = blockIdx.y;
  if (c >= 2048) return;
  float m = -1e30f;
  for (int s = 0; s < 500; ++s) m = fmaxf(m, s2[((size_t)(b * 500 + s)) * 2048 + c]);
  float sum = 0.0f, acc = 0.0f;
  for (int s = 0; s < 500; ++s) {
    size_t idx = ((size_t)(b * 500 + s)) * 2048 + c;
    float e = expf(s2[idx] - m);
    sum += e;
    acc += e * Ci[idx];
  }
  utt[(size_t)b * 2048 + c] = acc / sum;
}

// ---------------- launcher ----------------
extern "C" void kernel_launch(void* const* d_in, const int* in_sizes, int n_in,
                              void* d_out, int out_size, void* d_ws, size_t ws_size,
                              hipStream_t stream) {
  (void)in_sizes; (void)n_in; (void)out_size;
  float* utt = (float*)d_out;            // f32 [64][2048]
  float* Ci  = (float*)d_out + 131072;   // f32 [32000][2048]

  const float* x     = (const float*)d_in[0];
  const float* pos   = (const float*)d_in[1];
  const float* Wq_fw = (const float*)d_in[2];  const float* bq_fw = (const float*)d_in[3];
  const float* Wk_fw = (const float*)d_in[4];  const float* bk_fw = (const float*)d_in[5];
  const float* Wv_fw = (const float*)d_in[6];  const float* bv_fw = (const float*)d_in[7];
  const float* Wq_bw = (const float*)d_in[8];  const float* bq_bw = (const float*)d_in[9];
  const float* Wk_bw = (const float*)d_in[10]; const float* bk_bw = (const float*)d_in[11];
  const float* Wv_bw = (const float*)d_in[12]; const float* bv_bw = (const float*)d_in[13];
  const float* Wg_fw = (const float*)d_in[14]; const float* bg_fw = (const float*)d_in[15];
  const float* Wg_bw = (const float*)d_in[16]; const float* bg_bw = (const float*)d_in[17];
  const float* W2    = (const float*)d_in[18]; const float* b2    = (const float*)d_in[19];
  const float* W1    = (const float*)d_in[20]; const float* b1    = (const float*)d_in[21];

  // ws layout (bytes), total 399,769,600 (< 465,305,600 guard-proven):
  //  Hbf bf16 @0               ( 65,536,000)  } Cibf (131MB @0) after gates; s2b f32 after activ
  //  Q   bf16 @65,536,000      ( 65,536,000)  }
  //  K   bf16 @131,072,000     ( 65,536,000)  } activ bf16 (131MB @131,072,000) after attention
  //  Vt  bf16 @196,608,000     ( 67,108,864)  }   (Vt ends 263,716,864)
  //  S   f32  @263,716,864     ( 65,536,000)    alias Hm bf16 after softmax (ends 329,252,864)
  //  P   bf16 @329,252,864     ( 32,768,000)    (ends 362,020,864)
  //  wts bf16 @362,020,864     ( 37,748,736)    (ends 399,769,600)
  const size_t WS_BYTES = 399769600ull;
  if (ws_size < WS_BYTES) { fill_guard<<<512, 256, 0, stream>>>(utt, 500.0f); return; }

  char* wsb = (char*)d_ws;
  bf16*  Hbf  = (bf16*)(wsb);
  bf16*  Qb   = (bf16*)(wsb + 65536000);
  bf16*  Kb   = (bf16*)(wsb + 131072000);
  bf16*  Vt   = (bf16*)(wsb + 196608000);
  float* Sb   = (float*)(wsb + 263716864);
  bf16*  Hmb  = (bf16*)(wsb + 263716864);   // alias S after softmax
  bf16*  Pb   = (bf16*)(wsb + 329252864);
  char*  wts  = wsb + 362020864;
  bf16* WqF = (bf16*)(wts);             bf16* WkF = (bf16*)(wts + 2097152);
  bf16* WvF = (bf16*)(wts + 4194304);   bf16* WqB = (bf16*)(wts + 6291456);
  bf16* WkB = (bf16*)(wts + 8388608);   bf16* WvB = (bf16*)(wts + 10485760);
  bf16* WgF = (bf16*)(wts + 12582912);  bf16* WgB = (bf16*)(wts + 16777216);
  bf16* W2t = (bf16*)(wts + 20971520);  bf16* W1t = (bf16*)(wts + 29360128);
  bf16*  Cibf  = (bf16*)(wsb);              // alias Hbf+Q (post-gates)
  bf16*  activ = (bf16*)(wsb + 131072000);  // alias K+Vt head (post-attention, 131MB fits)
  float* s2b   = (float*)(wsb);             // alias Cibf (post-activ)

  add_pos_bf<<<32000, 256, 0, stream>>>(x, pos, Hbf);

  struct WT { const float* s; bf16* d; int R, C; } wt[10] = {
      {Wq_fw, WqF, 1024, 1024}, {Wk_fw, WkF, 1024, 1024}, {Wv_fw, WvF, 1024, 1024},
      {Wq_bw, WqB, 1024, 1024}, {Wk_bw, WkB, 1024, 1024}, {Wv_bw, WvB, 1024, 1024},
      {Wg_fw, WgF, 2048, 1024}, {Wg_bw, WgB, 2048, 1024},
      {W2,    W2t, 2048, 2048}, {W1,    W1t, 2048, 2048}};
  for (int i = 0; i < 10; ++i)
    wtrans<<<dim3(wt[i].C / 32, wt[i].R / 32), 256, 0, stream>>>(wt[i].s, wt[i].d, wt[i].R, wt[i].C);

  const int BIG = 1 << 30;
  for (int dir = 0; dir < 2; ++dir) {
    const bf16* WqT = dir ? WqB : WqF;  const float* bq = dir ? bq_bw : bq_fw;
    const bf16* WkT = dir ? WkB : WkF;  const float* bk = dir ? bk_bw : bk_fw;
    const bf16* WvT = dir ? WvB : WvF;  const float* bv = dir ? bv_bw : bv_fw;
    const bf16* WgT = dir ? WgB : WgF;  const float* bg = dir ? bg_bw : bg_fw;

    // Q/K = H @ W + b   [32000,1024]
    mgemm<0, bf16><<<dim3(8, 250, 1), 256, 0, stream>>>(
        Hbf, Hbf, BIG, WqT, bq, Qb, 32000, 1024, 1024, 1024, 1024, 1024, 0, 1.0f,
        0, 0, 0, nullptr, nullptr);
    mgemm<0, bf16><<<dim3(8, 250, 1), 256, 0, stream>>>(
        Hbf, Hbf, BIG, WkT, bk, Kb, 32000, 1024, 1024, 1024, 1024, 1024, 0, 1.0f,
        0, 0, 0, nullptr, nullptr);
    // V written directly transposed per batch: Vt[b][d][s]
    mgemm<3, bf16><<<dim3(8, 250, 1), 256, 0, stream>>>(
        Hbf, Hbf, BIG, WvT, bv, Vt, 32000, 1024, 1024, 1024, 1024, 512, 0, 1.0f,
        0, 0, 0, nullptr, nullptr);
    // S = Q K^T / 32   f32 [64][500][512]
    mgemm<0, float><<<dim3(4, 4, 64), 256, 0, stream>>>(
        Qb, Qb, BIG, Kb, nullptr, Sb, 500, 500, 1024, 1024, 1024, 512, 0, 0.03125f,
        512000, 512000, 256000, nullptr, nullptr);
    // P = masked softmax(S)  bf16 (pads zero)
    attn_softmax_p<<<125, 256, 0, stream>>>(Sb, Pb, dir == 0 ? 1 : 0);
    // Hm = P @ V   (K=512, P pads zero) -> overwrites S region
    mgemm<0, bf16><<<dim3(8, 4, 64), 256, 0, stream>>>(
        Pb, Pb, BIG, Vt, nullptr, Hmb, 500, 1024, 512, 512, 512, 1024, 0, 1.0f,
        256000, 524288, 512000, nullptr, nullptr);
    // C_i half = gate mix, f32 into d_out
    mgemm<2, float><<<dim3(8, 250, 1), 256, 0, stream>>>(
        Hbf, Hmb, 1024, WgT, bg, Ci, 32000, 1024, 2048, 1024, 2048, 2048,
        dir == 0 ? 0 : 1024, 1.0f, 0, 0, 0, Hbf, Hmb);
  }

  // Ci -> bf16 copy (Hbf/Q region, both dead)
  ci2bf<<<64000, 256, 0, stream>>>(Ci, Cibf);

  // activ = sigmoid(Cibf @ W2 + b2) -> bf16 over K/Vt region
  mgemm<1, bf16><<<dim3(16, 250, 1), 256, 0, stream>>>(
      Cibf, Cibf, BIG, W2t, b2, activ, 32000, 2048, 2048, 2048, 2048, 2048, 0, 1.0f,
      0, 0, 0, nullptr, nullptr);

  // scores2 + final reduce in 2 chunks of 32 batches (s2b over Cibf region)
  for (int c0 = 0; c0 < 2; ++c0) {
    mgemm<0, float><<<dim3(16, 125, 1), 256, 0, stream>>>(
        activ + (size_t)c0 * 16000 * 2048, activ, BIG, W1t, b1, s2b,
        16000, 2048, 2048, 2048, 2048, 2048, 0, 1.0f, 0, 0, 0, nullptr, nullptr);
    final_reduce_chunk<<<dim3(8, 32), 256, 0, stream>>>(
        s2b, Ci + (size_t)c0 * 32 * 500 * 2048, utt + (size_t)c0 * 32 * 2048);
  }
}

// Round 16
// 2884.192 us; speedup vs baseline: 10.2339x; 1.2399x over previous
//
#include <hip/hip_runtime.h>

typedef __bf16 bf16;
typedef __bf16 bf16x4 __attribute__((ext_vector_type(4)));
typedef __bf16 bf16x8 __attribute__((ext_vector_type(8)));
typedef float  f32x4  __attribute__((ext_vector_type(4)));
typedef unsigned int u32;

#define GLD_LDS16(gsrc, ldst) \
  __builtin_amdgcn_global_load_lds((const __attribute__((address_space(1))) u32*)(gsrc), \
                                   (__attribute__((address_space(3))) u32*)(ldst), 16, 0, 0)

static __device__ __forceinline__ float sigmoidf_(float x) { return 1.0f / (1.0f + expf(-x)); }

__global__ void fill_guard(float* __restrict__ utt, float v) {
  int i = blockIdx.x * 256 + threadIdx.x;
  if (i < 131072) utt[i] = v;
}

// ---------------- H = bf16(x + pos_emb) ----------------
__global__ void add_pos_bf(const float* __restrict__ x, const float* __restrict__ pos,
                           bf16* __restrict__ H) {
  size_t i = ((size_t)blockIdx.x * 256 + threadIdx.x) * 4;
  if (i >= 32768000ull) return;
  int d = (int)(i & 1023);
  int s = (int)((i >> 10) % 500);
  float4 xv = *(const float4*)(x + i);
  float4 pv = *(const float4*)(pos + (size_t)s * 1024 + d);
  bf16x4 o;
  o[0] = (bf16)(xv.x + pv.x); o[1] = (bf16)(xv.y + pv.y);
  o[2] = (bf16)(xv.z + pv.z); o[3] = (bf16)(xv.w + pv.w);
  *(bf16x4*)(H + i) = o;
}

// ---------------- weight transpose+convert: fp32 [R][C] -> bf16 [C][R] ----------------
__global__ void wtrans(const float* __restrict__ src, bf16* __restrict__ dst, int R, int C) {
  __shared__ float tile[32][33];
  int c0 = blockIdx.x * 32, r0 = blockIdx.y * 32;
  int tr = threadIdx.x >> 5, tc = threadIdx.x & 31;
#pragma unroll
  for (int i = 0; i < 4; ++i)
    tile[tr + i * 8][tc] = src[(size_t)(r0 + tr + i * 8) * C + c0 + tc];
  __syncthreads();
#pragma unroll
  for (int i = 0; i < 4; ++i) {
    int rr = tr + i * 8;
    dst[(size_t)(c0 + rr) * R + r0 + tc] = (bf16)tile[tc][rr];
  }
}

// ---------------- Ci f32 -> bf16 convert ----------------
__global__ void ci2bf(const float* __restrict__ src, bf16* __restrict__ dst) {
  size_t i = ((size_t)blockIdx.x * 256 + threadIdx.x) * 4;
  if (i >= 65536000ull) return;
  float4 v = *(const float4*)(src + i);
  bf16x4 o;
  o[0] = (bf16)v.x; o[1] = (bf16)v.y; o[2] = (bf16)v.z; o[3] = (bf16)v.w;
  *(bf16x4*)(dst + i) = o;
}

// ---------------- MFMA GEMM, global_load_lds staging, all-bf16 operands ----------------
// C[m,n] = scale*sum_k A[m,k]*Bt[n,k] (+bias[n]) + epilogue.  128x128 tile, BK=32, 4 waves.
// A split at ksplit -> A2 (same lda). EPI 0: plain. 1: sigmoid. 2: gate mix
// v=g*Gh[m,n]+(1-g)*Gm[m,n] (both bf16 [*,1024]). 3: V^T write C[b*524288+n*512+s], m=b*500+s.
template <int EPI, typename TC>
__global__ __launch_bounds__(256, 2) void mgemm(
    const bf16* __restrict__ A, const bf16* __restrict__ A2, int ksplit,
    const bf16* __restrict__ Bt, const float* __restrict__ bias, TC* __restrict__ C,
    int M, int N, int K, int lda, int ldb, int ldc, int c_off, float scale,
    long long sA, long long sB, long long sC,
    const bf16* __restrict__ Gh, const bf16* __restrict__ Gm) {
  __shared__ __align__(16) char sm[16384];  // A tile [128][32] @0, B tile @8192
  const int t = threadIdx.x;
  const long long bz = blockIdx.z;
  A += bz * sA; A2 += bz * sA; Bt += bz * sB; C += bz * sC;
  const int m0 = blockIdx.y * 128, n0 = blockIdx.x * 128;

  f32x4 acc[4][4];
#pragma unroll
  for (int i = 0; i < 4; ++i)
#pragma unroll
    for (int j = 0; j < 4; ++j)
#pragma unroll
      for (int c = 0; c < 4; ++c) acc[i][j][c] = 0.0f;

  const int lane = t & 63;
  const int wv = t >> 6, wm = (wv >> 1) * 64, wn = (wv & 1) * 64;
  const int lr = lane & 15, lkb = (lane >> 4) * 16;
  const int rr = t >> 2, cc = (t & 3) * 8;

  for (int k0 = 0; k0 < K; k0 += 32) {
    const bf16* Ak = (k0 < ksplit) ? (A + k0) : (A2 + (k0 - ksplit));
    const bf16* Bk = Bt + k0;
#pragma unroll
    for (int j = 0; j < 2; ++j) {
      int ra = m0 + j * 64 + rr; ra = ra < M ? ra : M - 1;
      GLD_LDS16(Ak + (size_t)ra * lda + cc, sm + j * 4096 + t * 16);
      int rb = n0 + j * 64 + rr; rb = rb < N ? rb : N - 1;
      GLD_LDS16(Bk + (size_t)rb * ldb + cc, sm + 8192 + j * 4096 + t * 16);
    }
    asm volatile("s_waitcnt vmcnt(0)" ::: "memory");
    __syncthreads();

    bf16x8 av[4], bv[4];
#pragma unroll
    for (int i = 0; i < 4; ++i) {
      av[i] = *(const bf16x8*)(sm + (wm + i * 16 + lr) * 64 + lkb);
      bv[i] = *(const bf16x8*)(sm + 8192 + (wn + i * 16 + lr) * 64 + lkb);
    }
#pragma unroll
    for (int i = 0; i < 4; ++i)
#pragma unroll
      for (int j = 0; j < 4; ++j)
        acc[i][j] = __builtin_amdgcn_mfma_f32_16x16x32_bf16(av[i], bv[j], acc[i][j], 0, 0, 0);
    __syncthreads();
  }

  // D elem j4 of frag (i,j): row = wm+i*16+(lane>>4)*4+j4, col = wn+j*16+(lane&15)
#pragma unroll
  for (int i = 0; i < 4; ++i) {
#pragma unroll
    for (int j4 = 0; j4 < 4; ++j4) {
      int m = m0 + wm + i * 16 + (lane >> 4) * 4 + j4;
      if (m >= M) continue;
#pragma unroll
      for (int j = 0; j < 4; ++j) {
        int n = n0 + wn + j * 16 + (lane & 15);
        if (n >= N) continue;
        float v = acc[i][j][j4] * scale;
        if (bias) v += bias[n];
        if (EPI == 1) v = sigmoidf_(v);
        if (EPI == 2) {
          float g = sigmoidf_(v);
          float h  = (float)Gh[(size_t)m * 1024 + n];
          float hm = (float)Gm[(size_t)m * 1024 + n];
          v = g * h + (1.0f - g) * hm;
        }
        if (EPI == 3) {
          unsigned b = (unsigned)m / 500u;
          unsigned s = (unsigned)m - b * 500u;
          C[(size_t)b * 524288 + (size_t)n * 512 + s] = (TC)v;
        } else {
          C[(size_t)m * ldc + c_off + n] = (TC)v;
        }
      }
    }
  }
}

// ---------------- masked softmax, WAVE-PARALLEL: one 64-lane wave per row ----------------
// S f32 [32000][512] -> P bf16 (pads+masked zero). fw: keep k<=q; bw: keep q<=k<500.
__global__ void attn_softmax_w(const float* __restrict__ S, bf16* __restrict__ P, int fw) {
  int row = blockIdx.x * 4 + (threadIdx.x >> 6);  // 8000 blocks x 4 waves
  int lane = threadIdx.x & 63;
  int q = row % 500;
  const float* Srow = S + (size_t)row * 512;
  bf16* Prow = P + (size_t)row * 512;
  int klo = fw ? 0 : q;
  int khi = fw ? q : 499;

  float xv[8];
  float m = -1e30f;
#pragma unroll
  for (int i = 0; i < 8; ++i) {
    int k = lane + i * 64;
    bool valid = (k >= klo) & (k <= khi);
    float v = valid ? Srow[k] : -1e30f;
    xv[i] = v;
    m = fmaxf(m, v);
  }
#pragma unroll
  for (int off = 32; off > 0; off >>= 1) m = fmaxf(m, __shfl_xor(m, off, 64));
  float e[8];
  float sum = 0.0f;
#pragma unroll
  for (int i = 0; i < 8; ++i) {
    e[i] = (xv[i] > -1e29f) ? expf(xv[i] - m) : 0.0f;
    sum += e[i];
  }
#pragma unroll
  for (int off = 32; off > 0; off >>= 1) sum += __shfl_xor(sum, off, 64);
  float inv = 1.0f / sum;
#pragma unroll
  for (int i = 0; i < 8; ++i) Prow[lane + i * 64] = (bf16)(e[i] * inv);
}

// ---------------- final: softmax over seq + weighted sum (per 32-batch chunk) ----------
__global__ void final_reduce_chunk(const float* __restrict__ s2, const float* __restrict__ Ci,
                                   float* __restrict__ utt) {
  int c = blockIdx.x * 256 + threadIdx.x;
  int b = blockIdx.y;
  if (c >= 2048) return;
  float m = -1e30f;
  for (int s = 0; s < 500; ++s) m = fmaxf(m, s2[((size_t)(b * 500 + s)) * 2048 + c]);
  float sum = 0.0f, acc = 0.0f;
  for (int s = 0; s < 500; ++s) {
    size_t idx = ((size_t)(b * 500 + s)) * 2048 + c;
    float e = expf(s2[idx] - m);
    sum += e;
    acc += e * Ci[idx];
  }
  utt[(size_t)b * 2048 + c] = acc / sum;
}

// ---------------- launcher ----------------
extern "C" void kernel_launch(void* const* d_in, const int* in_sizes, int n_in,
                              void* d_out, int out_size, void* d_ws, size_t ws_size,
                              hipStream_t stream) {
  (void)in_sizes; (void)n_in; (void)out_size;
  float* utt = (float*)d_out;            // f32 [64][2048]
  float* Ci  = (float*)d_out + 131072;   // f32 [32000][2048]

  const float* x     = (const float*)d_in[0];
  const float* pos   = (const float*)d_in[1];
  const float* Wq_fw = (const float*)d_in[2];  const float* bq_fw = (const float*)d_in[3];
  const float* Wk_fw = (const float*)d_in[4];  const float* bk_fw = (const float*)d_in[5];
  const float* Wv_fw = (const float*)d_in[6];  const float* bv_fw = (const float*)d_in[7];
  const float* Wq_bw = (const float*)d_in[8];  const float* bq_bw = (const float*)d_in[9];
  const float* Wk_bw = (const float*)d_in[10]; const float* bk_bw = (const float*)d_in[11];
  const float* Wv_bw = (const float*)d_in[12]; const float* bv_bw = (const float*)d_in[13];
  const float* Wg_fw = (const float*)d_in[14]; const float* bg_fw = (const float*)d_in[15];
  const float* Wg_bw = (const float*)d_in[16]; const float* bg_bw = (const float*)d_in[17];
  const float* W2    = (const float*)d_in[18]; const float* b2    = (const float*)d_in[19];
  const float* W1    = (const float*)d_in[20]; const float* b1    = (const float*)d_in[21];

  // ws layout (bytes), total 399,769,600 (< 465,305,600 guard-proven):
  //  Hbf bf16 @0               ( 65,536,000)  } Cibf (131MB @0) after gates; s2b f32 after activ
  //  Q   bf16 @65,536,000      ( 65,536,000)  }
  //  K   bf16 @131,072,000     ( 65,536,000)  } activ bf16 (131MB @131,072,000) after attention
  //  Vt  bf16 @196,608,000     ( 67,108,864)  }   (Vt ends 263,716,864)
  //  S   f32  @263,716,864     ( 65,536,000)    alias Hm bf16 after softmax (ends 329,252,864)
  //  P   bf16 @329,252,864     ( 32,768,000)    (ends 362,020,864)
  //  wts bf16 @362,020,864     ( 37,748,736)    (ends 399,769,600)
  const size_t WS_BYTES = 399769600ull;
  if (ws_size < WS_BYTES) { fill_guard<<<512, 256, 0, stream>>>(utt, 500.0f); return; }

  char* wsb = (char*)d_ws;
  bf16*  Hbf  = (bf16*)(wsb);
  bf16*  Qb   = (bf16*)(wsb + 65536000);
  bf16*  Kb   = (bf16*)(wsb + 131072000);
  bf16*  Vt   = (bf16*)(wsb + 196608000);
  float* Sb   = (float*)(wsb + 263716864);
  bf16*  Hmb  = (bf16*)(wsb + 263716864);   // alias S after softmax
  bf16*  Pb   = (bf16*)(wsb + 329252864);
  char*  wts  = wsb + 362020864;
  bf16* WqF = (bf16*)(wts);             bf16* WkF = (bf16*)(wts + 2097152);
  bf16* WvF = (bf16*)(wts + 4194304);   bf16* WqB = (bf16*)(wts + 6291456);
  bf16* WkB = (bf16*)(wts + 8388608);   bf16* WvB = (bf16*)(wts + 10485760);
  bf16* WgF = (bf16*)(wts + 12582912);  bf16* WgB = (bf16*)(wts + 16777216);
  bf16* W2t = (bf16*)(wts + 20971520);  bf16* W1t = (bf16*)(wts + 29360128);
  bf16*  Cibf  = (bf16*)(wsb);              // alias Hbf+Q (post-gates)
  bf16*  activ = (bf16*)(wsb + 131072000);  // alias K+Vt head (post-attention)
  float* s2b   = (float*)(wsb);             // alias Cibf (post-activ)

  add_pos_bf<<<32000, 256, 0, stream>>>(x, pos, Hbf);

  struct WT { const float* s; bf16* d; int R, C; } wt[10] = {
      {Wq_fw, WqF, 1024, 1024}, {Wk_fw, WkF, 1024, 1024}, {Wv_fw, WvF, 1024, 1024},
      {Wq_bw, WqB, 1024, 1024}, {Wk_bw, WkB, 1024, 1024}, {Wv_bw, WvB, 1024, 1024},
      {Wg_fw, WgF, 2048, 1024}, {Wg_bw, WgB, 2048, 1024},
      {W2,    W2t, 2048, 2048}, {W1,    W1t, 2048, 2048}};
  for (int i = 0; i < 10; ++i)
    wtrans<<<dim3(wt[i].C / 32, wt[i].R / 32), 256, 0, stream>>>(wt[i].s, wt[i].d, wt[i].R, wt[i].C);

  const int BIG = 1 << 30;
  for (int dir = 0; dir < 2; ++dir) {
    const bf16* WqT = dir ? WqB : WqF;  const float* bq = dir ? bq_bw : bq_fw;
    const bf16* WkT = dir ? WkB : WkF;  const float* bk = dir ? bk_bw : bk_fw;
    const bf16* WvT = dir ? WvB : WvF;  const float* bv = dir ? bv_bw : bv_fw;
    const bf16* WgT = dir ? WgB : WgF;  const float* bg = dir ? bg_bw : bg_fw;

    // Q/K = H @ W + b   [32000,1024]
    mgemm<0, bf16><<<dim3(8, 250, 1), 256, 0, stream>>>(
        Hbf, Hbf, BIG, WqT, bq, Qb, 32000, 1024, 1024, 1024, 1024, 1024, 0, 1.0f,
        0, 0, 0, nullptr, nullptr);
    mgemm<0, bf16><<<dim3(8, 250, 1), 256, 0, stream>>>(
        Hbf, Hbf, BIG, WkT, bk, Kb, 32000, 1024, 1024, 1024, 1024, 1024, 0, 1.0f,
        0, 0, 0, nullptr, nullptr);
    // V written directly transposed per batch: Vt[b][d][s]
    mgemm<3, bf16><<<dim3(8, 250, 1), 256, 0, stream>>>(
        Hbf, Hbf, BIG, WvT, bv, Vt, 32000, 1024, 1024, 1024, 1024, 512, 0, 1.0f,
        0, 0, 0, nullptr, nullptr);
    // S = Q K^T / 32   f32 [64][500][512]
    mgemm<0, float><<<dim3(4, 4, 64), 256, 0, stream>>>(
        Qb, Qb, BIG, Kb, nullptr, Sb, 500, 500, 1024, 1024, 1024, 512, 0, 0.03125f,
        512000, 512000, 256000, nullptr, nullptr);
    // P = masked softmax(S)  bf16 (pads zero) — wave-parallel
    attn_softmax_w<<<8000, 256, 0, stream>>>(Sb, Pb, dir == 0 ? 1 : 0);
    // Hm = P @ V   (K=512, P pads zero) -> overwrites S region
    mgemm<0, bf16><<<dim3(8, 4, 64), 256, 0, stream>>>(
        Pb, Pb, BIG, Vt, nullptr, Hmb, 500, 1024, 512, 512, 512, 1024, 0, 1.0f,
        256000, 524288, 512000, nullptr, nullptr);
    // C_i half = gate mix, f32 into d_out
    mgemm<2, float><<<dim3(8, 250, 1), 256, 0, stream>>>(
        Hbf, Hmb, 1024, WgT, bg, Ci, 32000, 1024, 2048, 1024, 2048, 2048,
        dir == 0 ? 0 : 1024, 1.0f, 0, 0, 0, Hbf, Hmb);
  }

  // Ci -> bf16 copy (Hbf/Q region, both dead)
  ci2bf<<<64000, 256, 0, stream>>>(Ci, Cibf);

  // activ = sigmoid(Cibf @ W2 + b2) -> bf16 over K/Vt region
  mgemm<1, bf16><<<dim3(16, 250, 1), 256, 0, stream>>>(
      Cibf, Cibf, BIG, W2t, b2, activ, 32000, 2048, 2048, 2048, 2048, 2048, 0, 1.0f,
      0, 0, 0, nullptr, nullptr);

  // scores2 + final reduce in 2 chunks of 32 batches (s2b over Cibf region)
  for (int c0 = 0; c0 < 2; ++c0) {
    mgemm<0, float><<<dim3(16, 125, 1), 256, 0, stream>>>(
        activ + (size_t)c0 * 16000 * 2048, activ, BIG, W1t, b1, s2b,
        16000, 2048, 2048, 2048, 2048, 2048, 0, 1.0f, 0, 0, 0, nullptr, nullptr);
    final_reduce_chunk<<<dim3(8, 32), 256, 0, stream>>>(
        s2b, Ci + (size_t)c0 * 32 * 500 * 2048, utt + (size_t)c0 * 32 * 2048);
  }
}

// Round 17
// 2610.301 us; speedup vs baseline: 11.3077x; 1.1049x over previous
//
#include <hip/hip_runtime.h>

typedef __bf16 bf16;
typedef __bf16 bf16x4 __attribute__((ext_vector_type(4)));
typedef __bf16 bf16x8 __attribute__((ext_vector_type(8)));
typedef float  f32x4  __attribute__((ext_vector_type(4)));
typedef unsigned int u32;

#define GLD_LDS16(gsrc, ldst) \
  __builtin_amdgcn_global_load_lds((const __attribute__((address_space(1))) u32*)(gsrc), \
                                   (__attribute__((address_space(3))) u32*)(ldst), 16, 0, 0)

static __device__ __forceinline__ float sigmoidf_(float x) { return 1.0f / (1.0f + expf(-x)); }

__global__ void fill_guard(float* __restrict__ utt, float v) {
  int i = blockIdx.x * 256 + threadIdx.x;
  if (i < 131072) utt[i] = v;
}

// ---------------- H = bf16(x + pos_emb) ----------------
__global__ void add_pos_bf(const float* __restrict__ x, const float* __restrict__ pos,
                           bf16* __restrict__ H) {
  size_t i = ((size_t)blockIdx.x * 256 + threadIdx.x) * 4;
  if (i >= 32768000ull) return;
  int d = (int)(i & 1023);
  int s = (int)((i >> 10) % 500);
  float4 xv = *(const float4*)(x + i);
  float4 pv = *(const float4*)(pos + (size_t)s * 1024 + d);
  bf16x4 o;
  o[0] = (bf16)(xv.x + pv.x); o[1] = (bf16)(xv.y + pv.y);
  o[2] = (bf16)(xv.z + pv.z); o[3] = (bf16)(xv.w + pv.w);
  *(bf16x4*)(H + i) = o;
}

// ---------------- weight transpose+convert: fp32 [R][C] -> bf16 [C][R] ----------------
__global__ void wtrans(const float* __restrict__ src, bf16* __restrict__ dst, int R, int C) {
  __shared__ float tile[32][33];
  int c0 = blockIdx.x * 32, r0 = blockIdx.y * 32;
  int tr = threadIdx.x >> 5, tc = threadIdx.x & 31;
#pragma unroll
  for (int i = 0; i < 4; ++i)
    tile[tr + i * 8][tc] = src[(size_t)(r0 + tr + i * 8) * C + c0 + tc];
  __syncthreads();
#pragma unroll
  for (int i = 0; i < 4; ++i) {
    int rr = tr + i * 8;
    dst[(size_t)(c0 + rr) * R + r0 + tc] = (bf16)tile[tc][rr];
  }
}

// ---------------- MFMA GEMM, global_load_lds staging, XCD-swizzled blocks ----------------
// C[m,n] = scale*sum_k A[m,k]*Bt[n,k] (+bias[n]) + epilogue.  128x128 tile, BK=32, 4 waves.
// A split at ksplit -> A2 (same lda). EPI 0: plain. 1: sigmoid. 2: gate mix
// v=g*Gh[m,n]+(1-g)*Gm[m,n] (+ optional bf16 dual-write to Cbf[m*2048+c_off+n]).
// EPI 3: V^T write C[b*524288+n*512+s], m=b*500+s.
template <int EPI, typename TC>
__global__ __launch_bounds__(256, 2) void mgemm(
    const bf16* __restrict__ A, const bf16* __restrict__ A2, int ksplit,
    const bf16* __restrict__ Bt, const float* __restrict__ bias, TC* __restrict__ C,
    bf16* __restrict__ Cbf,
    int M, int N, int K, int lda, int ldb, int ldc, int c_off, float scale,
    long long sA, long long sB, long long sC,
    const bf16* __restrict__ Gh, const bf16* __restrict__ Gm) {
  __shared__ __align__(16) char sm[16384];  // A tile [128][32] @0, B tile @8192
  const int t = threadIdx.x;
  const long long bz = blockIdx.z;
  A += bz * sA; A2 += bz * sA; Bt += bz * sB; C += bz * sC;

  // XCD-aware bijective block remap (m204): each XCD gets a contiguous chunk of
  // the row-major (y,x) space -> neighboring tiles (shared A/B panels) co-locate in L2.
  const int gx = gridDim.x;
  const int nwg = gx * gridDim.y;
  const int orig = blockIdx.y * gx + blockIdx.x;
  const int qq = nwg >> 3, r8 = nwg & 7;
  const int xcd = orig & 7, lo = orig >> 3;
  const int wg = (xcd < r8 ? xcd * (qq + 1) : r8 * (qq + 1) + (xcd - r8) * qq) + lo;
  const int m0 = (wg / gx) * 128, n0 = (wg % gx) * 128;

  f32x4 acc[4][4];
#pragma unroll
  for (int i = 0; i < 4; ++i)
#pragma unroll
    for (int j = 0; j < 4; ++j)
#pragma unroll
      for (int c = 0; c < 4; ++c) acc[i][j][c] = 0.0f;

  const int lane = t & 63;
  const int wv = t >> 6, wm = (wv >> 1) * 64, wn = (wv & 1) * 64;
  const int lr = lane & 15, lkb = (lane >> 4) * 16;
  const int rr = t >> 2, cc = (t & 3) * 8;

  for (int k0 = 0; k0 < K; k0 += 32) {
    const bf16* Ak = (k0 < ksplit) ? (A + k0) : (A2 + (k0 - ksplit));
    const bf16* Bk = Bt + k0;
#pragma unroll
    for (int j = 0; j < 2; ++j) {
      int ra = m0 + j * 64 + rr; ra = ra < M ? ra : M - 1;
      GLD_LDS16(Ak + (size_t)ra * lda + cc, sm + j * 4096 + t * 16);
      int rb = n0 + j * 64 + rr; rb = rb < N ? rb : N - 1;
      GLD_LDS16(Bk + (size_t)rb * ldb + cc, sm + 8192 + j * 4096 + t * 16);
    }
    asm volatile("s_waitcnt vmcnt(0)" ::: "memory");
    __syncthreads();

    bf16x8 av[4], bv[4];
#pragma unroll
    for (int i = 0; i < 4; ++i) {
      av[i] = *(const bf16x8*)(sm + (wm + i * 16 + lr) * 64 + lkb);
      bv[i] = *(const bf16x8*)(sm + 8192 + (wn + i * 16 + lr) * 64 + lkb);
    }
#pragma unroll
    for (int i = 0; i < 4; ++i)
#pragma unroll
      for (int j = 0; j < 4; ++j)
        acc[i][j] = __builtin_amdgcn_mfma_f32_16x16x32_bf16(av[i], bv[j], acc[i][j], 0, 0, 0);
    __syncthreads();
  }

  // D elem j4 of frag (i,j): row = wm+i*16+(lane>>4)*4+j4, col = wn+j*16+(lane&15)
#pragma unroll
  for (int i = 0; i < 4; ++i) {
#pragma unroll
    for (int j4 = 0; j4 < 4; ++j4) {
      int m = m0 + wm + i * 16 + (lane >> 4) * 4 + j4;
      if (m >= M) continue;
#pragma unroll
      for (int j = 0; j < 4; ++j) {
        int n = n0 + wn + j * 16 + (lane & 15);
        if (n >= N) continue;
        float v = acc[i][j][j4] * scale;
        if (bias) v += bias[n];
        if (EPI == 1) v = sigmoidf_(v);
        if (EPI == 2) {
          float g = sigmoidf_(v);
          float h  = (float)Gh[(size_t)m * 1024 + n];
          float hm = (float)Gm[(size_t)m * 1024 + n];
          v = g * h + (1.0f - g) * hm;
        }
        if (EPI == 3) {
          unsigned b = (unsigned)m / 500u;
          unsigned s = (unsigned)m - b * 500u;
          C[(size_t)b * 524288 + (size_t)n * 512 + s] = (TC)v;
        } else {
          C[(size_t)m * ldc + c_off + n] = (TC)v;
          if (EPI == 2 && Cbf) Cbf[(size_t)m * 2048 + c_off + n] = (bf16)v;
        }
      }
    }
  }
}

// ---------------- masked softmax, WAVE-PARALLEL: one 64-lane wave per row ----------------
__global__ void attn_softmax_w(const float* __restrict__ S, bf16* __restrict__ P, int fw) {
  int row = blockIdx.x * 4 + (threadIdx.x >> 6);
  int lane = threadIdx.x & 63;
  int q = row % 500;
  const float* Srow = S + (size_t)row * 512;
  bf16* Prow = P + (size_t)row * 512;
  int klo = fw ? 0 : q;
  int khi = fw ? q : 499;

  float xv[8];
  float m = -1e30f;
#pragma unroll
  for (int i = 0; i < 8; ++i) {
    int k = lane + i * 64;
    bool valid = (k >= klo) & (k <= khi);
    float v = valid ? Srow[k] : -1e30f;
    xv[i] = v;
    m = fmaxf(m, v);
  }
#pragma unroll
  for (int off = 32; off > 0; off >>= 1) m = fmaxf(m, __shfl_xor(m, off, 64));
  float e[8];
  float sum = 0.0f;
#pragma unroll
  for (int i = 0; i < 8; ++i) {
    e[i] = (xv[i] > -1e29f) ? expf(xv[i] - m) : 0.0f;
    sum += e[i];
  }
#pragma unroll
  for (int off = 32; off > 0; off >>= 1) sum += __shfl_xor(sum, off, 64);
  float inv = 1.0f / sum;
#pragma unroll
  for (int i = 0; i < 8; ++i) Prow[lane + i * 64] = (bf16)(e[i] * inv);
}

// ---------------- final: online softmax over seq + weighted sum (per 32-batch chunk) ----
__global__ void final_reduce_chunk(const float* __restrict__ s2, const float* __restrict__ Ci,
                                   float* __restrict__ utt) {
  int c = blockIdx.x * 256 + threadIdx.x;
  int b = blockIdx.y;
  if (c >= 2048) return;
  float m = -1e30f, sum = 0.0f, acc = 0.0f;
  for (int s = 0; s < 500; ++s) {
    size_t idx = ((size_t)(b * 500 + s)) * 2048 + c;
    float xx = s2[idx];
    float ci = Ci[idx];
    float mn = fmaxf(m, xx);
    float corr = expf(m - mn);
    float e = expf(xx - mn);
    sum = sum * corr + e;
    acc = acc * corr + e * ci;
    m = mn;
  }
  utt[(size_t)b * 2048 + c] = acc / sum;
}

// ---------------- launcher ----------------
extern "C" void kernel_launch(void* const* d_in, const int* in_sizes, int n_in,
                              void* d_out, int out_size, void* d_ws, size_t ws_size,
                              hipStream_t stream) {
  (void)in_sizes; (void)n_in; (void)out_size;
  float* utt = (float*)d_out;            // f32 [64][2048]
  float* Ci  = (float*)d_out + 131072;   // f32 [32000][2048]

  const float* x     = (const float*)d_in[0];
  const float* pos   = (const float*)d_in[1];
  const float* Wq_fw = (const float*)d_in[2];  const float* bq_fw = (const float*)d_in[3];
  const float* Wk_fw = (const float*)d_in[4];  const float* bk_fw = (const float*)d_in[5];
  const float* Wv_fw = (const float*)d_in[6];  const float* bv_fw = (const float*)d_in[7];
  const float* Wq_bw = (const float*)d_in[8];  const float* bq_bw = (const float*)d_in[9];
  const float* Wk_bw = (const float*)d_in[10]; const float* bk_bw = (const float*)d_in[11];
  const float* Wv_bw = (const float*)d_in[12]; const float* bv_bw = (const float*)d_in[13];
  const float* Wg_fw = (const float*)d_in[14]; const float* bg_fw = (const float*)d_in[15];
  const float* Wg_bw = (const float*)d_in[16]; const float* bg_bw = (const float*)d_in[17];
  const float* W2    = (const float*)d_in[18]; const float* b2    = (const float*)d_in[19];
  const float* W1    = (const float*)d_in[20]; const float* b1    = (const float*)d_in[21];

  // ws layout (bytes), total 465,305,600 (== guard-proven max):
  //  Hbf bf16 @0               ( 65,536,000)  } s2b f32 (131MB @0) after gates
  //  Q   bf16 @65,536,000      ( 65,536,000)  }
  //  K   bf16 @131,072,000     ( 65,536,000)  } activ bf16 (131MB @131,072,000) post-attention
  //  Vt  bf16 @196,608,000     ( 67,108,864)  }   (ends 263,716,864)
  //  S   f32  @263,716,864     ( 65,536,000)    alias Hm bf16 after softmax (ends 329,252,864)
  //  P   bf16 @329,252,864     ( 32,768,000)    (ends 362,020,864)
  //  wts bf16 @362,020,864     ( 37,748,736)    (ends 399,769,600)
  //  Cibf bf16 @399,769,600    ( 65,536,000)    (ends 465,305,600)  -- dedicated
  const size_t WS_BYTES = 465305600ull;
  if (ws_size < WS_BYTES) { fill_guard<<<512, 256, 0, stream>>>(utt, 500.0f); return; }

  char* wsb = (char*)d_ws;
  bf16*  Hbf  = (bf16*)(wsb);
  bf16*  Qb   = (bf16*)(wsb + 65536000);
  bf16*  Kb   = (bf16*)(wsb + 131072000);
  bf16*  Vt   = (bf16*)(wsb + 196608000);
  float* Sb   = (float*)(wsb + 263716864);
  bf16*  Hmb  = (bf16*)(wsb + 263716864);   // alias S after softmax
  bf16*  Pb   = (bf16*)(wsb + 329252864);
  char*  wts  = wsb + 362020864;
  bf16* WqF = (bf16*)(wts);             bf16* WkF = (bf16*)(wts + 2097152);
  bf16* WvF = (bf16*)(wts + 4194304);   bf16* WqB = (bf16*)(wts + 6291456);
  bf16* WkB = (bf16*)(wts + 8388608);   bf16* WvB = (bf16*)(wts + 10485760);
  bf16* WgF = (bf16*)(wts + 12582912);  bf16* WgB = (bf16*)(wts + 16777216);
  bf16* W2t = (bf16*)(wts + 20971520);  bf16* W1t = (bf16*)(wts + 29360128);
  bf16*  Cibf  = (bf16*)(wsb + 399769600);  // dedicated
  bf16*  activ = (bf16*)(wsb + 131072000);  // alias K+Vt head (post-attention)
  float* s2b   = (float*)(wsb);             // alias Hbf+Q (post-gates)

  add_pos_bf<<<32000, 256, 0, stream>>>(x, pos, Hbf);

  struct WT { const float* s; bf16* d; int R, C; } wt[10] = {
      {Wq_fw, WqF, 1024, 1024}, {Wk_fw, WkF, 1024, 1024}, {Wv_fw, WvF, 1024, 1024},
      {Wq_bw, WqB, 1024, 1024}, {Wk_bw, WkB, 1024, 1024}, {Wv_bw, WvB, 1024, 1024},
      {Wg_fw, WgF, 2048, 1024}, {Wg_bw, WgB, 2048, 1024},
      {W2,    W2t, 2048, 2048}, {W1,    W1t, 2048, 2048}};
  for (int i = 0; i < 10; ++i)
    wtrans<<<dim3(wt[i].C / 32, wt[i].R / 32), 256, 0, stream>>>(wt[i].s, wt[i].d, wt[i].R, wt[i].C);

  const int BIG = 1 << 30;
  for (int dir = 0; dir < 2; ++dir) {
    const bf16* WqT = dir ? WqB : WqF;  const float* bq = dir ? bq_bw : bq_fw;
    const bf16* WkT = dir ? WkB : WkF;  const float* bk = dir ? bk_bw : bk_fw;
    const bf16* WvT = dir ? WvB : WvF;  const float* bv = dir ? bv_bw : bv_fw;
    const bf16* WgT = dir ? WgB : WgF;  const float* bg = dir ? bg_bw : bg_fw;

    // Q/K = H @ W + b   [32000,1024]
    mgemm<0, bf16><<<dim3(8, 250, 1), 256, 0, stream>>>(
        Hbf, Hbf, BIG, WqT, bq, Qb, nullptr, 32000, 1024, 1024, 1024, 1024, 1024, 0, 1.0f,
        0, 0, 0, nullptr, nullptr);
    mgemm<0, bf16><<<dim3(8, 250, 1), 256, 0, stream>>>(
        Hbf, Hbf, BIG, WkT, bk, Kb, nullptr, 32000, 1024, 1024, 1024, 1024, 1024, 0, 1.0f,
        0, 0, 0, nullptr, nullptr);
    // V written directly transposed per batch: Vt[b][d][s]
    mgemm<3, bf16><<<dim3(8, 250, 1), 256, 0, stream>>>(
        Hbf, Hbf, BIG, WvT, bv, Vt, nullptr, 32000, 1024, 1024, 1024, 1024, 512, 0, 1.0f,
        0, 0, 0, nullptr, nullptr);
    // S = Q K^T / 32   f32 [64][500][512]
    mgemm<0, float><<<dim3(4, 4, 64), 256, 0, stream>>>(
        Qb, Qb, BIG, Kb, nullptr, Sb, nullptr, 500, 500, 1024, 1024, 1024, 512, 0, 0.03125f,
        512000, 512000, 256000, nullptr, nullptr);
    // P = masked softmax(S)  bf16 (pads zero) — wave-parallel
    attn_softmax_w<<<8000, 256, 0, stream>>>(Sb, Pb, dir == 0 ? 1 : 0);
    // Hm = P @ V   (K=512, P pads zero) -> overwrites S region
    mgemm<0, bf16><<<dim3(8, 4, 64), 256, 0, stream>>>(
        Pb, Pb, BIG, Vt, nullptr, Hmb, nullptr, 500, 1024, 512, 512, 512, 1024, 0, 1.0f,
        256000, 524288, 512000, nullptr, nullptr);
    // C_i half = gate mix: f32 into d_out + bf16 dual-write into Cibf
    mgemm<2, float><<<dim3(8, 250, 1), 256, 0, stream>>>(
        Hbf, Hmb, 1024, WgT, bg, Ci, Cibf, 32000, 1024, 2048, 1024, 2048, 2048,
        dir == 0 ? 0 : 1024, 1.0f, 0, 0, 0, Hbf, Hmb);
  }

  // activ = sigmoid(Cibf @ W2 + b2) -> bf16 over K/Vt region
  mgemm<1, bf16><<<dim3(16, 250, 1), 256, 0, stream>>>(
      Cibf, Cibf, BIG, W2t, b2, activ, nullptr, 32000, 2048, 2048, 2048, 2048, 2048, 0, 1.0f,
      0, 0, 0, nullptr, nullptr);

  // scores2 + online final reduce in 2 chunks of 32 batches (s2b over Hbf/Q region)
  for (int c0 = 0; c0 < 2; ++c0) {
    mgemm<0, float><<<dim3(16, 125, 1), 256, 0, stream>>>(
        activ + (size_t)c0 * 16000 * 2048, activ, BIG, W1t, b1, s2b, nullptr,
        16000, 2048, 2048, 2048, 2048, 2048, 0, 1.0f, 0, 0, 0, nullptr, nullptr);
    final_reduce_chunk<<<dim3(8, 32), 256, 0, stream>>>(
        s2b, Ci + (size_t)c0 * 32 * 500 * 2048, utt + (size_t)c0 * 32 * 2048);
  }
}